// Round 9
// baseline (432.752 us; speedup 1.0000x reference)
//
#include <hip/hip_runtime.h>
#include <hip/hip_fp16.h>
#include <math.h>

#define NANG 9
#define SS 16
#define NPIX 256
#define WSH 72                 // window row stride in half2 pairs; 72 mod 32 = 8
#define NROWW 70
#define WINSZH (NROWW * WSH)   // 5040 pair-dwords = 20160 B
#define NITEM (NANG * 16)      // 144 (angle, sub) items per image
#define NWAVE 8                // 512-thread blocks -> 4 blocks/CU x 8 waves = 32 waves/CU
#define IPW (NITEM / NWAVE)    // 18 items per wave
#define FLTMAX_BITS 0x7F7FFFFFu

// 16B per (angle, lane-slot):  (pixels are PERMUTED per angle for bank balance)
//  .x = half2 (ewx0, ewx1)           x-weights, block-validity folded in
//  .y = half2 (-s*ewy0, -s*ewy1)     NEGATED y-weights pre-scaled by s = sqrt(m/msum)
//  .z = f32 s
//  .w = off | (p << 16);  off = (y0+1)*WSH + (x0+1), p = original pixel index

__global__ __launch_bounds__(256) void build_table(uint4* __restrict__ tbl)
{
    __shared__ float red[256];
    __shared__ unsigned char clsArr[256];
    __shared__ int H[32];
    __shared__ int startArr[32];

    const int p  = threadIdx.x;
    const int px = p & 15, py = p >> 4;
    for (int a = 0; a < NANG; ++a) {
        double t  = (double)(a - 4) * 0.017453292519943295; // deg2rad
        double ca = cos(t), sa = sin(t);
        float sx = (float)(ca * px - sa * py + (1.0 - ca) * 8.0 + sa * 8.0);
        float sy = (float)(sa * px + ca * py - sa * 8.0 + (1.0 - ca) * 8.0);
        float x0f = floorf(sx), y0f = floorf(sy);
        int   x0  = (int)x0f,   y0  = (int)y0f;
        float wx1 = sx - x0f, wx0 = 1.0f - wx1;
        float wy1 = sy - y0f, wy0 = 1.0f - wy1;
        float ewx0 = (x0 >= 0 && x0 < SS)         ? wx0 : 0.0f;
        float ewx1 = (x0 + 1 >= 0 && x0 + 1 < SS) ? wx1 : 0.0f;
        float ewy0 = (y0 >= 0 && y0 < SS)         ? wy0 : 0.0f;
        float ewy1 = (y0 + 1 >= 0 && y0 + 1 < SS) ? wy1 : 0.0f;
        float m = (ewx0 + ewx1) * (ewy0 + ewy1);

        red[p] = m;
        __syncthreads();
        for (int s = 128; s > 0; s >>= 1) {
            if (p < s) red[p] += red[p + s];
            __syncthreads();
        }
        float msum = red[0];
        __syncthreads();

        float sc = sqrtf(m / msum);
        x0 = max(-1, min(15, x0));   // LDS bounds safety (weights encode validity)
        y0 = max(-1, min(15, y0));
        const int off = (y0 + 1) * WSH + (x0 + 1);
        uint4 e;
        e.x = (unsigned)__half_as_ushort(__float2half(ewx0)) |
              ((unsigned)__half_as_ushort(__float2half(ewx1)) << 16);
        e.y = (unsigned)__half_as_ushort(__float2half(-sc * ewy0)) |
              ((unsigned)__half_as_ushort(__float2half(-sc * ewy1)) << 16);
        e.z = __float_as_uint(sc);
        e.w = (unsigned)off | ((unsigned)p << 16);

        // ---- per-angle pixel permutation: balance LDS bank classes ----
        // bank of every window read for this pixel ≡ off mod 32 (all other
        // address terms are uniform mod 32). Deal pixels round-robin by class
        // into 4 k-groups of 64 so each wave read tiles banks ~2-way.
        const int cls = off & 31;
        clsArr[p] = (unsigned char)cls;
        __syncthreads();
        int rank = 0;                              // deterministic stable rank
        for (int q = 0; q < 256; ++q)
            rank += (clsArr[q] == (unsigned char)cls) && (q < p);
        if (p < 32) {
            int h = 0;
            for (int q = 0; q < 256; ++q) h += (clsArr[q] == (unsigned char)p);
            H[p] = h;
        }
        __syncthreads();
        if (p == 0) {
            int acc = 0;
            for (int c = 0; c < 32; ++c) { startArr[c] = acc; acc += H[c]; }
        }
        __syncthreads();
        const int s    = startArr[cls] + rank;     // sorted-by-class position
        const int nidx = (s & 3) * 64 + (s >> 2);  // k-group, lane
        tbl[a * NPIX + nidx] = e;
        __syncthreads();
    }
}

// butterfly-sum across 64 lanes on the VALU pipe; full sum lands in lane 63
#define DPPADD(v, ctrl, rmask)                                                   \
    v += __int_as_float(__builtin_amdgcn_update_dpp(                             \
            0, __float_as_int(v), ctrl, rmask, 0xf, true))

// Load one pair-row per k and packed-x-interp into h[k][0..NP-1] (half2 pairs).
template<int NP>
__device__ __forceinline__ void rowload(const __half2* __restrict__ winh,
                                        int (&addr)[4],
                                        const __half2 (&wx0)[4], const __half2 (&wx1)[4],
                                        __half2 (&h)[4][NP])
{
    #pragma unroll
    for (int k = 0; k < 4; ++k) {
        __half2 d[2 * NP];
        #pragma unroll
        for (int j = 0; j < 2 * NP; ++j) d[j] = winh[addr[k] + j];  // ds_read2_b32
        #pragma unroll
        for (int c = 0; c < NP; ++c)
            h[k][c] = __hfma2(wx1[k], d[2 * c + 1], __hmul2(wx0[k], d[2 * c]));
        addr[k] += WSH;
    }
}

// One by-step: packed y-interp + square-acc (2 bx per op), unpack, DPP-reduce,
// min over the (compile-time) valid bx count, atomicMin into submin[sub].
template<int NP>
__device__ __forceinline__ void bystep(const __half2 (&hp)[4][NP], const __half2 (&hc)[4][NP],
                                       const __half2 (&wy0n)[4], const __half2 (&wy1n)[4],
                                       const __half2 (&r1s)[4],
                                       unsigned* __restrict__ sm, int lane)
{
    __half2 acc[NP];
    #pragma unroll
    for (int c = 0; c < NP; ++c) acc[c] = __floats2half2_rn(0.f, 0.f);
    #pragma unroll
    for (int k = 0; k < 4; ++k) {
        #pragma unroll
        for (int c = 0; c < NP; ++c) {
            __half2 e = __hfma2(wy0n[k], hp[k][c], r1s[k]);  // r1s - wys0*hp
            e = __hfma2(wy1n[k], hc[k][c], e);               //     - wys1*hc
            acc[c] = __hfma2(e, e, acc[c]);
        }
    }
    constexpr int NJ = 2 * NP - 1;     // valid bx count: NP=5 -> 9, NP=3 -> 5
    float v[NJ];
    #pragma unroll
    for (int c = 0; c < NP; ++c) {
        v[2 * c] = __low2float(acc[c]);
        if (2 * c + 1 < NJ) v[2 * c + 1] = __high2float(acc[c]);
    }
    #pragma unroll
    for (int j = 0; j < NJ; ++j) {
        DPPADD(v[j], 0xB1,  0xf);   // xor 1
        DPPADD(v[j], 0x4E,  0xf);   // xor 2
        DPPADD(v[j], 0x141, 0xf);   // row_half_mirror (xor 4)
        DPPADD(v[j], 0x140, 0xf);   // row_mirror      (xor 8)
        DPPADD(v[j], 0x142, 0xa);   // row_bcast:15 -> rows 1,3
        DPPADD(v[j], 0x143, 0xc);   // row_bcast:31 -> rows 2,3
    }
    if (lane == 63) {
        float best = v[0];
        #pragma unroll
        for (int j = 1; j < NJ; ++j) best = fminf(best, v[j]);
        atomicMin(sm, __float_as_uint(best));   // scores >= 0: uint order == float order
    }
}

template<int NBY, int NP>
__device__ __forceinline__ void proc(const __half2* __restrict__ winh, int (&addr)[4],
                                     const __half2 (&wx0)[4], const __half2 (&wx1)[4],
                                     const __half2 (&wy0n)[4], const __half2 (&wy1n)[4],
                                     const __half2 (&r1s)[4],
                                     unsigned* __restrict__ sm, int lane)
{
    __half2 hA[4][NP], hB[4][NP];
    rowload<NP>(winh, addr, wx0, wx1, hA);
    #pragma unroll
    for (int by = 0; by < NBY + 1; by += 2) {
        rowload<NP>(winh, addr, wx0, wx1, hB);
        bystep<NP>(hA, hB, wy0n, wy1n, r1s, sm, lane);
        if (by + 1 < NBY + 1) {
            rowload<NP>(winh, addr, wx0, wx1, hA);
            bystep<NP>(hB, hA, wy0n, wy1n, r1s, sm, lane);
        }
    }
}

// One block per image, 8 waves (512 threads) -> 32 waves/CU. Item = (angle,
// sub), 18/wave. Pixels are bank-balance-permuted per angle (see build_table);
// r1 is gathered per item with offsets precomputed at angle reload (L1-hot).
__global__ __launch_bounds__(512) void randip_main(const float* __restrict__ fm1,
                                                   const float* __restrict__ fm2,
                                                   const uint4* __restrict__ gt,
                                                   float* __restrict__ out)
{
    __shared__ __half2 winh[WINSZH];    // 20160 B: pair c = (w[c-1], w[c]), f16
    __shared__ unsigned submin[16];

    const int b    = blockIdx.x;
    const int tid  = threadIdx.x;
    const int wave = tid >> 6;
    const int lane = tid & 63;

    for (int i = tid; i < WINSZH; i += 512) winh[i] = __floats2half2_rn(0.f, 0.f);
    if (tid < 16) submin[tid] = FLTMAX_BITS;
    __syncthreads();

    // fill pair-window: buffer (r+1, c) = (img2[r][c-1], img2[r][c])
    const float* img2 = fm2 + (size_t)b * 4096;
    for (int i = tid; i < 64 * 65; i += 512) {
        int r = i / 65, c = i - r * 65;
        float lo = (c >= 1)  ? img2[r * 64 + c - 1] : 0.f;
        float hi = (c <= 63) ? img2[r * 64 + c]     : 0.f;
        winh[(r + 1) * WSH + c] = __floats2half2_rn(lo, hi);
    }
    __syncthreads();

    const float* img1 = fm1 + (size_t)b * 4096;

    int a_cur = -1;
    __half2 wx0[4], wx1[4], wy0n[4], wy1n[4], r1s[4];
    float   sca[4];
    int     off[4], o1[4];

    for (int i = wave * IPW; i < (wave + 1) * IPW; ++i) {
        const int a = i >> 4, sub = i & 15;
        if (a != a_cur) {                     // <=2 reloads per wave, coalesced b128
            a_cur = a;
            const uint4* tp = gt + a * NPIX + lane;
            #pragma unroll
            for (int k = 0; k < 4; ++k) {
                uint4 te = tp[64 * k];
                __half2 X = *(const __half2*)&te.x;
                __half2 Y = *(const __half2*)&te.y;
                wx0[k]  = __half2half2(__low2half(X));
                wx1[k]  = __half2half2(__high2half(X));
                wy0n[k] = __half2half2(__low2half(Y));
                wy1n[k] = __half2half2(__high2half(Y));
                sca[k]  = __uint_as_float(te.z);
                off[k]  = (int)(te.w & 0xffffu);
                const int p = (int)(te.w >> 16);
                o1[k]  = (p >> 4) * 64 + (p & 15);   // img1-relative pixel offset
            }
        }
        const int sub_x = (sub & 3) << 4;
        const int sub_y = (sub >> 2) << 4;
        const int x_lo = max(sub_x - 4, 0);
        const int y_lo = max(sub_y - 4, 0);
        const int nvx = min(sub_x + 4, 48) - x_lo;   // 4 or 8
        const int nby = min(sub_y + 4, 48) - y_lo;   // 4 or 8
        const int rowbase0 = y_lo * WSH + x_lo;

        const float* img1sub = img1 + sub_y * 64 + sub_x;
        #pragma unroll
        for (int k = 0; k < 4; ++k)
            r1s[k] = __float2half2_rn(sca[k] * img1sub[o1[k]]);   // L1-hot gather

        int addr[4];
        #pragma unroll
        for (int k = 0; k < 4; ++k) addr[k] = rowbase0 + off[k];

        unsigned* sm = &submin[sub];
        if (nby == 8) {
            if (nvx == 8) proc<8, 5>(winh, addr, wx0, wx1, wy0n, wy1n, r1s, sm, lane);
            else          proc<8, 3>(winh, addr, wx0, wx1, wy0n, wy1n, r1s, sm, lane);
        } else {
            if (nvx == 8) proc<4, 5>(winh, addr, wx0, wx1, wy0n, wy1n, r1s, sm, lane);
            else          proc<4, 3>(winh, addr, wx0, wx1, wy0n, wy1n, r1s, sm, lane);
        }
    }
    __syncthreads();

    if (tid == 0) {
        float t = 0.0f;
        #pragma unroll
        for (int s = 0; s < 16; ++s) t += __uint_as_float(submin[s]);
        out[b] = t;
    }
}

extern "C" void kernel_launch(void* const* d_in, const int* in_sizes, int n_in,
                              void* d_out, int out_size, void* d_ws, size_t ws_size,
                              hipStream_t stream)
{
    const float* fm1 = (const float*)d_in[0];
    const float* fm2 = (const float*)d_in[1];
    float* out = (float*)d_out;
    uint4* tbl = (uint4*)d_ws;   // 36,864 B scratch

    const int nb = in_sizes[0] >> 12;   // 1024 images of 64*64

    hipLaunchKernelGGL(build_table, dim3(1), dim3(256), 0, stream, tbl);
    hipLaunchKernelGGL(randip_main, dim3(nb), dim3(512), 0, stream, fm1, fm2, tbl, out);
}

// Round 10
// 418.994 us; speedup vs baseline: 1.0328x; 1.0328x over previous
//
#include <hip/hip_runtime.h>
#include <hip/hip_fp16.h>
#include <math.h>

#define NANG 9
#define SS 16
#define NPIX 256
#define WSH 72                 // window row stride in half2 pairs; 72 mod 32 = 8
#define NROWW 70
#define WINSZH (NROWW * WSH)   // 5040 pair-dwords = 20160 B
#define NITEM (NANG * 16)      // 144 (angle, sub) items per image
#define NWAVE 8                // 512-thread blocks -> 4 blocks/CU x 8 waves = 32 waves/CU
#define IPW (NITEM / NWAVE)    // 18 items per wave
#define FLTMAX_BITS 0x7F7FFFFFu

// 16B per (angle, lane-slot):  (pixels are PERMUTED per angle for bank balance)
//  .x = half2 (ewx0, ewx1)           x-weights, block-validity folded in
//  .y = half2 (-s*ewy0, -s*ewy1)     NEGATED y-weights pre-scaled by s = sqrt(m/msum)
//  .z = f32 s
//  .w = off | (p << 16);  off = (y0+1)*WSH + (x0+1), p = original pixel index

__global__ __launch_bounds__(256) void build_table(uint4* __restrict__ tbl)
{
    __shared__ float red[256];
    __shared__ unsigned char clsArr[256];
    __shared__ int H[32];
    __shared__ int startArr[32];

    const int p  = threadIdx.x;
    const int px = p & 15, py = p >> 4;
    for (int a = 0; a < NANG; ++a) {
        double t  = (double)(a - 4) * 0.017453292519943295; // deg2rad
        double ca = cos(t), sa = sin(t);
        float sx = (float)(ca * px - sa * py + (1.0 - ca) * 8.0 + sa * 8.0);
        float sy = (float)(sa * px + ca * py - sa * 8.0 + (1.0 - ca) * 8.0);
        float x0f = floorf(sx), y0f = floorf(sy);
        int   x0  = (int)x0f,   y0  = (int)y0f;
        float wx1 = sx - x0f, wx0 = 1.0f - wx1;
        float wy1 = sy - y0f, wy0 = 1.0f - wy1;
        float ewx0 = (x0 >= 0 && x0 < SS)         ? wx0 : 0.0f;
        float ewx1 = (x0 + 1 >= 0 && x0 + 1 < SS) ? wx1 : 0.0f;
        float ewy0 = (y0 >= 0 && y0 < SS)         ? wy0 : 0.0f;
        float ewy1 = (y0 + 1 >= 0 && y0 + 1 < SS) ? wy1 : 0.0f;
        float m = (ewx0 + ewx1) * (ewy0 + ewy1);

        red[p] = m;
        __syncthreads();
        for (int s = 128; s > 0; s >>= 1) {
            if (p < s) red[p] += red[p + s];
            __syncthreads();
        }
        float msum = red[0];
        __syncthreads();

        float sc = sqrtf(m / msum);
        x0 = max(-1, min(15, x0));   // LDS bounds safety (weights encode validity)
        y0 = max(-1, min(15, y0));
        const int off = (y0 + 1) * WSH + (x0 + 1);
        uint4 e;
        e.x = (unsigned)__half_as_ushort(__float2half(ewx0)) |
              ((unsigned)__half_as_ushort(__float2half(ewx1)) << 16);
        e.y = (unsigned)__half_as_ushort(__float2half(-sc * ewy0)) |
              ((unsigned)__half_as_ushort(__float2half(-sc * ewy1)) << 16);
        e.z = __float_as_uint(sc);
        e.w = (unsigned)off | ((unsigned)p << 16);

        // ---- per-angle pixel permutation: balance LDS bank classes ----
        // bank of every window read for this pixel ≡ off mod 32 (all other
        // address terms are uniform mod 32). LDS serves wave64 in TWO 32-lane
        // phases (R9 evidence: same-phase clustering raised conflicts 43%).
        // Deal class-sorted position s as: k-group = s&3, lane = (s>>3) +
        // 32*((s>>2)&1) -> the two same-class copies per k-group sit at lanes
        // c and c+32 (opposite phases). Uniform histogram (8/class) then gives
        // each phase 32 distinct banks exactly once: conflict-free.
        const int cls = off & 31;
        clsArr[p] = (unsigned char)cls;
        __syncthreads();
        int rank = 0;                              // deterministic stable rank
        for (int q = 0; q < 256; ++q)
            rank += (clsArr[q] == (unsigned char)cls) && (q < p);
        if (p < 32) {
            int h = 0;
            for (int q = 0; q < 256; ++q) h += (clsArr[q] == (unsigned char)p);
            H[p] = h;
        }
        __syncthreads();
        if (p == 0) {
            int acc = 0;
            for (int c = 0; c < 32; ++c) { startArr[c] = acc; acc += H[c]; }
        }
        __syncthreads();
        const int s      = startArr[cls] + rank;   // sorted-by-class position
        const int lane_n = (s >> 3) + (((s >> 2) & 1) << 5);
        const int nidx   = (s & 3) * 64 + lane_n;  // k-group, phase-split lane
        tbl[a * NPIX + nidx] = e;
        __syncthreads();
    }
}

// butterfly-sum across 64 lanes on the VALU pipe; full sum lands in lane 63
#define DPPADD(v, ctrl, rmask)                                                   \
    v += __int_as_float(__builtin_amdgcn_update_dpp(                             \
            0, __float_as_int(v), ctrl, rmask, 0xf, true))

// Load one pair-row per k and packed-x-interp into h[k][0..NP-1] (half2 pairs).
template<int NP>
__device__ __forceinline__ void rowload(const __half2* __restrict__ winh,
                                        int (&addr)[4],
                                        const __half2 (&wx0)[4], const __half2 (&wx1)[4],
                                        __half2 (&h)[4][NP])
{
    #pragma unroll
    for (int k = 0; k < 4; ++k) {
        __half2 d[2 * NP];
        #pragma unroll
        for (int j = 0; j < 2 * NP; ++j) d[j] = winh[addr[k] + j];  // ds_read2_b32
        #pragma unroll
        for (int c = 0; c < NP; ++c)
            h[k][c] = __hfma2(wx1[k], d[2 * c + 1], __hmul2(wx0[k], d[2 * c]));
        addr[k] += WSH;
    }
}

// One by-step: packed y-interp + square-acc (2 bx per op), unpack, DPP-reduce,
// min over the (compile-time) valid bx count, atomicMin into submin[sub].
template<int NP>
__device__ __forceinline__ void bystep(const __half2 (&hp)[4][NP], const __half2 (&hc)[4][NP],
                                       const __half2 (&wy0n)[4], const __half2 (&wy1n)[4],
                                       const __half2 (&r1s)[4],
                                       unsigned* __restrict__ sm, int lane)
{
    __half2 acc[NP];
    #pragma unroll
    for (int c = 0; c < NP; ++c) acc[c] = __floats2half2_rn(0.f, 0.f);
    #pragma unroll
    for (int k = 0; k < 4; ++k) {
        #pragma unroll
        for (int c = 0; c < NP; ++c) {
            __half2 e = __hfma2(wy0n[k], hp[k][c], r1s[k]);  // r1s - wys0*hp
            e = __hfma2(wy1n[k], hc[k][c], e);               //     - wys1*hc
            acc[c] = __hfma2(e, e, acc[c]);
        }
    }
    constexpr int NJ = 2 * NP - 1;     // valid bx count: NP=5 -> 9, NP=3 -> 5
    float v[NJ];
    #pragma unroll
    for (int c = 0; c < NP; ++c) {
        v[2 * c] = __low2float(acc[c]);
        if (2 * c + 1 < NJ) v[2 * c + 1] = __high2float(acc[c]);
    }
    #pragma unroll
    for (int j = 0; j < NJ; ++j) {
        DPPADD(v[j], 0xB1,  0xf);   // xor 1
        DPPADD(v[j], 0x4E,  0xf);   // xor 2
        DPPADD(v[j], 0x141, 0xf);   // row_half_mirror (xor 4)
        DPPADD(v[j], 0x140, 0xf);   // row_mirror      (xor 8)
        DPPADD(v[j], 0x142, 0xa);   // row_bcast:15 -> rows 1,3
        DPPADD(v[j], 0x143, 0xc);   // row_bcast:31 -> rows 2,3
    }
    if (lane == 63) {
        float best = v[0];
        #pragma unroll
        for (int j = 1; j < NJ; ++j) best = fminf(best, v[j]);
        atomicMin(sm, __float_as_uint(best));   // scores >= 0: uint order == float order
    }
}

template<int NBY, int NP>
__device__ __forceinline__ void proc(const __half2* __restrict__ winh, int (&addr)[4],
                                     const __half2 (&wx0)[4], const __half2 (&wx1)[4],
                                     const __half2 (&wy0n)[4], const __half2 (&wy1n)[4],
                                     const __half2 (&r1s)[4],
                                     unsigned* __restrict__ sm, int lane)
{
    __half2 hA[4][NP], hB[4][NP];
    rowload<NP>(winh, addr, wx0, wx1, hA);
    #pragma unroll
    for (int by = 0; by < NBY + 1; by += 2) {
        rowload<NP>(winh, addr, wx0, wx1, hB);
        bystep<NP>(hA, hB, wy0n, wy1n, r1s, sm, lane);
        if (by + 1 < NBY + 1) {
            rowload<NP>(winh, addr, wx0, wx1, hA);
            bystep<NP>(hB, hA, wy0n, wy1n, r1s, sm, lane);
        }
    }
}

// One block per image, 8 waves (512 threads) -> 32 waves/CU. Item = (angle,
// sub), 18/wave. Pixels are phase-aware bank-permuted per angle (build_table);
// r1 is gathered per item with offsets precomputed at angle reload (L1-hot).
__global__ __launch_bounds__(512) void randip_main(const float* __restrict__ fm1,
                                                   const float* __restrict__ fm2,
                                                   const uint4* __restrict__ gt,
                                                   float* __restrict__ out)
{
    __shared__ __half2 winh[WINSZH];    // 20160 B: pair c = (w[c-1], w[c]), f16
    __shared__ unsigned submin[16];

    const int b    = blockIdx.x;
    const int tid  = threadIdx.x;
    const int wave = tid >> 6;
    const int lane = tid & 63;

    for (int i = tid; i < WINSZH; i += 512) winh[i] = __floats2half2_rn(0.f, 0.f);
    if (tid < 16) submin[tid] = FLTMAX_BITS;
    __syncthreads();

    // fill pair-window: buffer (r+1, c) = (img2[r][c-1], img2[r][c])
    const float* img2 = fm2 + (size_t)b * 4096;
    for (int i = tid; i < 64 * 65; i += 512) {
        int r = i / 65, c = i - r * 65;
        float lo = (c >= 1)  ? img2[r * 64 + c - 1] : 0.f;
        float hi = (c <= 63) ? img2[r * 64 + c]     : 0.f;
        winh[(r + 1) * WSH + c] = __floats2half2_rn(lo, hi);
    }
    __syncthreads();

    const float* img1 = fm1 + (size_t)b * 4096;

    int a_cur = -1;
    __half2 wx0[4], wx1[4], wy0n[4], wy1n[4], r1s[4];
    float   sca[4];
    int     off[4], o1[4];

    for (int i = wave * IPW; i < (wave + 1) * IPW; ++i) {
        const int a = i >> 4, sub = i & 15;
        if (a != a_cur) {                     // <=2 reloads per wave, coalesced b128
            a_cur = a;
            const uint4* tp = gt + a * NPIX + lane;
            #pragma unroll
            for (int k = 0; k < 4; ++k) {
                uint4 te = tp[64 * k];
                __half2 X = *(const __half2*)&te.x;
                __half2 Y = *(const __half2*)&te.y;
                wx0[k]  = __half2half2(__low2half(X));
                wx1[k]  = __half2half2(__high2half(X));
                wy0n[k] = __half2half2(__low2half(Y));
                wy1n[k] = __half2half2(__high2half(Y));
                sca[k]  = __uint_as_float(te.z);
                off[k]  = (int)(te.w & 0xffffu);
                const int p = (int)(te.w >> 16);
                o1[k]  = (p >> 4) * 64 + (p & 15);   // img1-relative pixel offset
            }
        }
        const int sub_x = (sub & 3) << 4;
        const int sub_y = (sub >> 2) << 4;
        const int x_lo = max(sub_x - 4, 0);
        const int y_lo = max(sub_y - 4, 0);
        const int nvx = min(sub_x + 4, 48) - x_lo;   // 4 or 8
        const int nby = min(sub_y + 4, 48) - y_lo;   // 4 or 8
        const int rowbase0 = y_lo * WSH + x_lo;

        const float* img1sub = img1 + sub_y * 64 + sub_x;
        #pragma unroll
        for (int k = 0; k < 4; ++k)
            r1s[k] = __float2half2_rn(sca[k] * img1sub[o1[k]]);   // L1-hot gather

        int addr[4];
        #pragma unroll
        for (int k = 0; k < 4; ++k) addr[k] = rowbase0 + off[k];

        unsigned* sm = &submin[sub];
        if (nby == 8) {
            if (nvx == 8) proc<8, 5>(winh, addr, wx0, wx1, wy0n, wy1n, r1s, sm, lane);
            else          proc<8, 3>(winh, addr, wx0, wx1, wy0n, wy1n, r1s, sm, lane);
        } else {
            if (nvx == 8) proc<4, 5>(winh, addr, wx0, wx1, wy0n, wy1n, r1s, sm, lane);
            else          proc<4, 3>(winh, addr, wx0, wx1, wy0n, wy1n, r1s, sm, lane);
        }
    }
    __syncthreads();

    if (tid == 0) {
        float t = 0.0f;
        #pragma unroll
        for (int s = 0; s < 16; ++s) t += __uint_as_float(submin[s]);
        out[b] = t;
    }
}

extern "C" void kernel_launch(void* const* d_in, const int* in_sizes, int n_in,
                              void* d_out, int out_size, void* d_ws, size_t ws_size,
                              hipStream_t stream)
{
    const float* fm1 = (const float*)d_in[0];
    const float* fm2 = (const float*)d_in[1];
    float* out = (float*)d_out;
    uint4* tbl = (uint4*)d_ws;   // 36,864 B scratch

    const int nb = in_sizes[0] >> 12;   // 1024 images of 64*64

    hipLaunchKernelGGL(build_table, dim3(1), dim3(256), 0, stream, tbl);
    hipLaunchKernelGGL(randip_main, dim3(nb), dim3(512), 0, stream, fm1, fm2, tbl, out);
}

// Round 11
// 372.260 us; speedup vs baseline: 1.1625x; 1.1255x over previous
//
#include <hip/hip_runtime.h>
#include <hip/hip_fp16.h>
#include <math.h>

#define NANG 9
#define SS 16
#define NPIX 256
#define WSH 72                 // window row stride in half2 pairs; 72 mod 32 = 8
#define NROWW 70
#define WINSZH (NROWW * WSH)   // 5040 pair-dwords = 20160 B
#define NITEM (NANG * 16)      // 144 (angle, sub) items per image
#define NWAVE 8                // 512-thread blocks -> 4 blocks/CU x 8 waves = 32 waves/CU
#define IPW (NITEM / NWAVE)    // 18 items per wave
#define FLTMAX_BITS 0x7F7FFFFFu

// 16B per (angle, lane-slot):  (pixels are PERMUTED per angle for bank balance)
//  .x = half2 (ewx0, ewx1)           x-weights, block-validity folded in
//  .y = half2 (-s*ewy0, -s*ewy1)     NEGATED y-weights pre-scaled by s = sqrt(m/msum)
//  .z = f32 s
//  .w = off | (p << 16);  off = (y0+1)*WSH + (x0+1), p = original pixel index

__global__ __launch_bounds__(256) void build_table(uint4* __restrict__ tbl)
{
    __shared__ float red[256];
    __shared__ int histo[4 * 32];      // per-wave per-class counts
    __shared__ int startArr[32];

    const int p  = threadIdx.x;
    const int wv = p >> 6, ln = p & 63;
    const int px = p & 15, py = p >> 4;
    for (int a = 0; a < NANG; ++a) {
        double t  = (double)(a - 4) * 0.017453292519943295; // deg2rad
        double ca = cos(t), sa = sin(t);
        float sx = (float)(ca * px - sa * py + (1.0 - ca) * 8.0 + sa * 8.0);
        float sy = (float)(sa * px + ca * py - sa * 8.0 + (1.0 - ca) * 8.0);
        float x0f = floorf(sx), y0f = floorf(sy);
        int   x0  = (int)x0f,   y0  = (int)y0f;
        float wx1 = sx - x0f, wx0 = 1.0f - wx1;
        float wy1 = sy - y0f, wy0 = 1.0f - wy1;
        float ewx0 = (x0 >= 0 && x0 < SS)         ? wx0 : 0.0f;
        float ewx1 = (x0 + 1 >= 0 && x0 + 1 < SS) ? wx1 : 0.0f;
        float ewy0 = (y0 >= 0 && y0 < SS)         ? wy0 : 0.0f;
        float ewy1 = (y0 + 1 >= 0 && y0 + 1 < SS) ? wy1 : 0.0f;
        float m = (ewx0 + ewx1) * (ewy0 + ewy1);

        red[p] = m;
        __syncthreads();
        for (int s = 128; s > 0; s >>= 1) {
            if (p < s) red[p] += red[p + s];
            __syncthreads();
        }
        float msum = red[0];
        __syncthreads();

        float sc = sqrtf(m / msum);
        x0 = max(-1, min(15, x0));   // LDS bounds safety (weights encode validity)
        y0 = max(-1, min(15, y0));
        const int off = (y0 + 1) * WSH + (x0 + 1);
        uint4 e;
        e.x = (unsigned)__half_as_ushort(__float2half(ewx0)) |
              ((unsigned)__half_as_ushort(__float2half(ewx1)) << 16);
        e.y = (unsigned)__half_as_ushort(__float2half(-sc * ewy0)) |
              ((unsigned)__half_as_ushort(__float2half(-sc * ewy1)) << 16);
        e.z = __float_as_uint(sc);
        e.w = (unsigned)off | ((unsigned)p << 16);

        // ---- per-angle pixel permutation: balance LDS bank classes ----
        // bank of every window read for this pixel ≡ off mod 32 (all other
        // address terms are uniform mod 32). LDS serves wave64 in TWO 32-lane
        // phases (R9/R10 evidence: phase-split dealing cut conflicts 10x).
        // Deal class-sorted position s as: k-group = s&3, lane = (s>>3) +
        // 32*((s>>2)&1) -> same-class copies per k-group sit at lanes c and
        // c+32 (opposite phases); uniform histograms tile each phase's 32
        // banks exactly once. Rank/histogram via wave ballots (fast + exact).
        const int cls = e.w & 31;    // off & 31
        unsigned long long mymask = 0;
        #pragma unroll
        for (int c = 0; c < 32; ++c) {
            unsigned long long mm = __ballot(cls == c);
            if (cls == c) mymask = mm;
            if (ln == c) histo[wv * 32 + c] = (int)__popcll(mm);
        }
        __syncthreads();
        int rank = (int)__popcll(mymask & ((1ull << ln) - 1ull));
        #pragma unroll
        for (int w = 0; w < 4; ++w)
            if (w < wv) rank += histo[w * 32 + cls];
        if (p < 32) {                        // start[c] = prefix of class totals
            int acc = 0;
            for (int c = 0; c < 32; ++c) {
                if (c == p) break;
                acc += histo[c] + histo[32 + c] + histo[64 + c] + histo[96 + c];
            }
            startArr[p] = acc;
        }
        __syncthreads();
        const int s      = startArr[cls] + rank;   // sorted-by-class position
        const int lane_n = (s >> 3) + (((s >> 2) & 1) << 5);
        const int nidx   = (s & 3) * 64 + lane_n;  // k-group, phase-split lane
        tbl[a * NPIX + nidx] = e;
        __syncthreads();
    }
}

// butterfly-sum across 64 lanes on the VALU pipe; full sum lands in lane 63
#define DPPADD(v, ctrl, rmask)                                                   \
    v += __int_as_float(__builtin_amdgcn_update_dpp(                             \
            0, __float_as_int(v), ctrl, rmask, 0xf, true))

// Load one pair-row per k and packed-x-interp into h[k][0..NP-1] (half2 pairs).
template<int NP>
__device__ __forceinline__ void rowload(const __half2* __restrict__ winh,
                                        int (&addr)[4],
                                        const __half2 (&wx0)[4], const __half2 (&wx1)[4],
                                        __half2 (&h)[4][NP])
{
    #pragma unroll
    for (int k = 0; k < 4; ++k) {
        __half2 d[2 * NP];
        #pragma unroll
        for (int j = 0; j < 2 * NP; ++j) d[j] = winh[addr[k] + j];  // ds_read2_b32
        #pragma unroll
        for (int c = 0; c < NP; ++c)
            h[k][c] = __hfma2(wx1[k], d[2 * c + 1], __hmul2(wx0[k], d[2 * c]));
        addr[k] += WSH;
    }
}

// One by-step: packed y-interp + square-acc (2 bx per op), unpack, DPP-reduce,
// min over the (compile-time) valid bx count, atomicMin into submin[sub].
template<int NP>
__device__ __forceinline__ void bystep(const __half2 (&hp)[4][NP], const __half2 (&hc)[4][NP],
                                       const __half2 (&wy0n)[4], const __half2 (&wy1n)[4],
                                       const __half2 (&r1s)[4],
                                       unsigned* __restrict__ sm, int lane)
{
    __half2 acc[NP];
    #pragma unroll
    for (int c = 0; c < NP; ++c) acc[c] = __floats2half2_rn(0.f, 0.f);
    #pragma unroll
    for (int k = 0; k < 4; ++k) {
        #pragma unroll
        for (int c = 0; c < NP; ++c) {
            __half2 e = __hfma2(wy0n[k], hp[k][c], r1s[k]);  // r1s - wys0*hp
            e = __hfma2(wy1n[k], hc[k][c], e);               //     - wys1*hc
            acc[c] = __hfma2(e, e, acc[c]);
        }
    }
    constexpr int NJ = 2 * NP - 1;     // valid bx count: NP=5 -> 9, NP=3 -> 5
    float v[NJ];
    #pragma unroll
    for (int c = 0; c < NP; ++c) {
        v[2 * c] = __low2float(acc[c]);
        if (2 * c + 1 < NJ) v[2 * c + 1] = __high2float(acc[c]);
    }
    #pragma unroll
    for (int j = 0; j < NJ; ++j) {
        DPPADD(v[j], 0xB1,  0xf);   // xor 1
        DPPADD(v[j], 0x4E,  0xf);   // xor 2
        DPPADD(v[j], 0x141, 0xf);   // row_half_mirror (xor 4)
        DPPADD(v[j], 0x140, 0xf);   // row_mirror      (xor 8)
        DPPADD(v[j], 0x142, 0xa);   // row_bcast:15 -> rows 1,3
        DPPADD(v[j], 0x143, 0xc);   // row_bcast:31 -> rows 2,3
    }
    if (lane == 63) {
        float best = v[0];
        #pragma unroll
        for (int j = 1; j < NJ; ++j) best = fminf(best, v[j]);
        atomicMin(sm, __float_as_uint(best));   // scores >= 0: uint order == float order
    }
}

template<int NBY, int NP>
__device__ __forceinline__ void proc(const __half2* __restrict__ winh, int (&addr)[4],
                                     const __half2 (&wx0)[4], const __half2 (&wx1)[4],
                                     const __half2 (&wy0n)[4], const __half2 (&wy1n)[4],
                                     const __half2 (&r1s)[4],
                                     unsigned* __restrict__ sm, int lane)
{
    __half2 hA[4][NP], hB[4][NP];
    rowload<NP>(winh, addr, wx0, wx1, hA);
    #pragma unroll
    for (int by = 0; by < NBY + 1; by += 2) {
        rowload<NP>(winh, addr, wx0, wx1, hB);
        bystep<NP>(hA, hB, wy0n, wy1n, r1s, sm, lane);
        if (by + 1 < NBY + 1) {
            rowload<NP>(winh, addr, wx0, wx1, hA);
            bystep<NP>(hB, hA, wy0n, wy1n, r1s, sm, lane);
        }
    }
}

// One block per image, 8 waves (512 threads) -> 32 waves/CU. Item = (angle,
// sub), 18/wave. Pixels are phase-aware bank-permuted per angle (build_table);
// r1 is gathered per item with offsets precomputed at angle reload (L1-hot).
__global__ __launch_bounds__(512) void randip_main(const float* __restrict__ fm1,
                                                   const float* __restrict__ fm2,
                                                   const uint4* __restrict__ gt,
                                                   float* __restrict__ out)
{
    __shared__ __half2 winh[WINSZH];    // 20160 B: pair c = (w[c-1], w[c]), f16
    __shared__ unsigned submin[16];

    const int b    = blockIdx.x;
    const int tid  = threadIdx.x;
    const int wave = tid >> 6;
    const int lane = tid & 63;

    for (int i = tid; i < WINSZH; i += 512) winh[i] = __floats2half2_rn(0.f, 0.f);
    if (tid < 16) submin[tid] = FLTMAX_BITS;
    __syncthreads();

    // fill pair-window: buffer (r+1, c) = (img2[r][c-1], img2[r][c])
    const float* img2 = fm2 + (size_t)b * 4096;
    for (int i = tid; i < 64 * 65; i += 512) {
        int r = i / 65, c = i - r * 65;
        float lo = (c >= 1)  ? img2[r * 64 + c - 1] : 0.f;
        float hi = (c <= 63) ? img2[r * 64 + c]     : 0.f;
        winh[(r + 1) * WSH + c] = __floats2half2_rn(lo, hi);
    }
    __syncthreads();

    const float* img1 = fm1 + (size_t)b * 4096;

    int a_cur = -1;
    __half2 wx0[4], wx1[4], wy0n[4], wy1n[4], r1s[4];
    float   sca[4];
    int     off[4], o1[4];

    for (int i = wave * IPW; i < (wave + 1) * IPW; ++i) {
        const int a = i >> 4, sub = i & 15;
        if (a != a_cur) {                     // <=2 reloads per wave, coalesced b128
            a_cur = a;
            const uint4* tp = gt + a * NPIX + lane;
            #pragma unroll
            for (int k = 0; k < 4; ++k) {
                uint4 te = tp[64 * k];
                __half2 X = *(const __half2*)&te.x;
                __half2 Y = *(const __half2*)&te.y;
                wx0[k]  = __half2half2(__low2half(X));
                wx1[k]  = __half2half2(__high2half(X));
                wy0n[k] = __half2half2(__low2half(Y));
                wy1n[k] = __half2half2(__high2half(Y));
                sca[k]  = __uint_as_float(te.z);
                off[k]  = (int)(te.w & 0xffffu);
                const int p = (int)(te.w >> 16);
                o1[k]  = (p >> 4) * 64 + (p & 15);   // img1-relative pixel offset
            }
        }
        const int sub_x = (sub & 3) << 4;
        const int sub_y = (sub >> 2) << 4;
        const int x_lo = max(sub_x - 4, 0);
        const int y_lo = max(sub_y - 4, 0);
        const int nvx = min(sub_x + 4, 48) - x_lo;   // 4 or 8
        const int nby = min(sub_y + 4, 48) - y_lo;   // 4 or 8
        const int rowbase0 = y_lo * WSH + x_lo;

        const float* img1sub = img1 + sub_y * 64 + sub_x;
        #pragma unroll
        for (int k = 0; k < 4; ++k)
            r1s[k] = __float2half2_rn(sca[k] * img1sub[o1[k]]);   // L1-hot gather

        int addr[4];
        #pragma unroll
        for (int k = 0; k < 4; ++k) addr[k] = rowbase0 + off[k];

        unsigned* sm = &submin[sub];
        if (nby == 8) {
            if (nvx == 8) proc<8, 5>(winh, addr, wx0, wx1, wy0n, wy1n, r1s, sm, lane);
            else          proc<8, 3>(winh, addr, wx0, wx1, wy0n, wy1n, r1s, sm, lane);
        } else {
            if (nvx == 8) proc<4, 5>(winh, addr, wx0, wx1, wy0n, wy1n, r1s, sm, lane);
            else          proc<4, 3>(winh, addr, wx0, wx1, wy0n, wy1n, r1s, sm, lane);
        }
    }
    __syncthreads();

    if (tid == 0) {
        float t = 0.0f;
        #pragma unroll
        for (int s = 0; s < 16; ++s) t += __uint_as_float(submin[s]);
        out[b] = t;
    }
}

extern "C" void kernel_launch(void* const* d_in, const int* in_sizes, int n_in,
                              void* d_out, int out_size, void* d_ws, size_t ws_size,
                              hipStream_t stream)
{
    const float* fm1 = (const float*)d_in[0];
    const float* fm2 = (const float*)d_in[1];
    float* out = (float*)d_out;
    uint4* tbl = (uint4*)d_ws;   // 36,864 B scratch

    const int nb = in_sizes[0] >> 12;   // 1024 images of 64*64

    hipLaunchKernelGGL(build_table, dim3(1), dim3(256), 0, stream, tbl);
    hipLaunchKernelGGL(randip_main, dim3(nb), dim3(512), 0, stream, fm1, fm2, tbl, out);
}

// Round 12
// 342.660 us; speedup vs baseline: 1.2629x; 1.0864x over previous
//
#include <hip/hip_runtime.h>
#include <hip/hip_fp16.h>
#include <math.h>

#define NANG 9
#define SS 16
#define NPIX 256
#define WSH 72                 // window row stride in half2 pairs; 72 mod 32 = 8
#define NROWW 70
#define WINSZH (NROWW * WSH)   // 5040 pair-dwords = 20160 B
#define NITEM (NANG * 16)      // 144 (angle, sub) items per image
#define NWAVE 8                // 512-thread blocks -> 4 blocks/CU x 8 waves = 32 waves/CU
#define IPW (NITEM / NWAVE)    // 18 items per wave
#define FLTMAX_BITS 0x7F7FFFFFu

// 16B per (angle, lane-slot):  (pixels are PERMUTED per angle for bank balance)
//  .x = half2 (ewx0, ewx1)           x-weights, block-validity folded in
//  .y = half2 (-s*ewy0, -s*ewy1)     NEGATED y-weights pre-scaled by s = sqrt(m/msum)
//  .z = f32 s
//  .w = off | (p << 16);  off = (y0+1)*WSH + (x0+1), p = original pixel index

// One block per ANGLE (grid=9): removes the 9x serialization that cost ~18 us
// per replay as a single-block kernel (R11 post-mortem).
__global__ __launch_bounds__(256) void build_table(uint4* __restrict__ tbl)
{
    __shared__ float red[256];
    __shared__ int histo[4 * 32];      // per-wave per-class counts
    __shared__ int startArr[32];

    const int a  = blockIdx.x;
    const int p  = threadIdx.x;
    const int wv = p >> 6, ln = p & 63;
    const int px = p & 15, py = p >> 4;

    double t  = (double)(a - 4) * 0.017453292519943295; // deg2rad
    double ca = cos(t), sa = sin(t);
    float sx = (float)(ca * px - sa * py + (1.0 - ca) * 8.0 + sa * 8.0);
    float sy = (float)(sa * px + ca * py - sa * 8.0 + (1.0 - ca) * 8.0);
    float x0f = floorf(sx), y0f = floorf(sy);
    int   x0  = (int)x0f,   y0  = (int)y0f;
    float wx1 = sx - x0f, wx0 = 1.0f - wx1;
    float wy1 = sy - y0f, wy0 = 1.0f - wy1;
    float ewx0 = (x0 >= 0 && x0 < SS)         ? wx0 : 0.0f;
    float ewx1 = (x0 + 1 >= 0 && x0 + 1 < SS) ? wx1 : 0.0f;
    float ewy0 = (y0 >= 0 && y0 < SS)         ? wy0 : 0.0f;
    float ewy1 = (y0 + 1 >= 0 && y0 + 1 < SS) ? wy1 : 0.0f;
    float m = (ewx0 + ewx1) * (ewy0 + ewy1);

    red[p] = m;
    __syncthreads();
    for (int s = 128; s > 0; s >>= 1) {
        if (p < s) red[p] += red[p + s];
        __syncthreads();
    }
    float msum = red[0];

    float sc = sqrtf(m / msum);
    x0 = max(-1, min(15, x0));   // LDS bounds safety (weights encode validity)
    y0 = max(-1, min(15, y0));
    const int off = (y0 + 1) * WSH + (x0 + 1);
    uint4 e;
    e.x = (unsigned)__half_as_ushort(__float2half(ewx0)) |
          ((unsigned)__half_as_ushort(__float2half(ewx1)) << 16);
    e.y = (unsigned)__half_as_ushort(__float2half(-sc * ewy0)) |
          ((unsigned)__half_as_ushort(__float2half(-sc * ewy1)) << 16);
    e.z = __float_as_uint(sc);
    e.w = (unsigned)off | ((unsigned)p << 16);

    // ---- per-angle pixel permutation: balance LDS bank classes ----
    // bank of every window read for this pixel ≡ off mod 32 (all other address
    // terms are uniform mod 32). LDS serves wave64 in TWO 32-lane phases
    // (R9/R10 evidence: phase-split dealing cut conflicts 10x). Deal
    // class-sorted position s as: k-group = s&3, lane = (s>>3) + 32*((s>>2)&1)
    // -> same-class copies per k-group sit at opposite phases; uniform
    // histograms tile each phase's 32 banks exactly once.
    const int cls = off & 31;
    unsigned long long mymask = 0;
    #pragma unroll
    for (int c = 0; c < 32; ++c) {
        unsigned long long mm = __ballot(cls == c);
        if (cls == c) mymask = mm;
        if (ln == c) histo[wv * 32 + c] = (int)__popcll(mm);
    }
    __syncthreads();
    int rank = (int)__popcll(mymask & ((1ull << ln) - 1ull));
    #pragma unroll
    for (int w = 0; w < 4; ++w)
        if (w < wv) rank += histo[w * 32 + cls];
    if (p < 32) {                        // start[c] = prefix of class totals
        int acc = 0;
        for (int c = 0; c < 32; ++c) {
            if (c == p) break;
            acc += histo[c] + histo[32 + c] + histo[64 + c] + histo[96 + c];
        }
        startArr[p] = acc;
    }
    __syncthreads();
    const int s      = startArr[cls] + rank;   // sorted-by-class position
    const int lane_n = (s >> 3) + (((s >> 2) & 1) << 5);
    const int nidx   = (s & 3) * 64 + lane_n;  // k-group, phase-split lane
    tbl[a * NPIX + nidx] = e;
}

// butterfly-sum across 64 lanes on the VALU pipe; full sum lands in lane 63
#define DPPADD(v, ctrl, rmask)                                                   \
    v += __int_as_float(__builtin_amdgcn_update_dpp(                             \
            0, __float_as_int(v), ctrl, rmask, 0xf, true))

// Load one pair-row per k and packed-x-interp into h[k][0..NP-1] (half2 pairs).
template<int NP>
__device__ __forceinline__ void rowload(const __half2* __restrict__ winh,
                                        int (&addr)[4],
                                        const __half2 (&wx0)[4], const __half2 (&wx1)[4],
                                        __half2 (&h)[4][NP])
{
    #pragma unroll
    for (int k = 0; k < 4; ++k) {
        __half2 d[2 * NP];
        #pragma unroll
        for (int j = 0; j < 2 * NP; ++j) d[j] = winh[addr[k] + j];  // ds_read2_b32
        #pragma unroll
        for (int c = 0; c < NP; ++c)
            h[k][c] = __hfma2(wx1[k], d[2 * c + 1], __hmul2(wx0[k], d[2 * c]));
        addr[k] += WSH;
    }
}

// One by-step: packed y-interp + square-acc (2 bx per op), unpack, DPP-reduce,
// min over the (compile-time) valid bx count, atomicMin into submin[sub].
template<int NP>
__device__ __forceinline__ void bystep(const __half2 (&hp)[4][NP], const __half2 (&hc)[4][NP],
                                       const __half2 (&wy0n)[4], const __half2 (&wy1n)[4],
                                       const __half2 (&r1s)[4],
                                       unsigned* __restrict__ sm, int lane)
{
    __half2 acc[NP];
    #pragma unroll
    for (int c = 0; c < NP; ++c) acc[c] = __floats2half2_rn(0.f, 0.f);
    #pragma unroll
    for (int k = 0; k < 4; ++k) {
        #pragma unroll
        for (int c = 0; c < NP; ++c) {
            __half2 e = __hfma2(wy0n[k], hp[k][c], r1s[k]);  // r1s - wys0*hp
            e = __hfma2(wy1n[k], hc[k][c], e);               //     - wys1*hc
            acc[c] = __hfma2(e, e, acc[c]);
        }
    }
    constexpr int NJ = 2 * NP - 1;     // valid bx count: NP=5 -> 9, NP=3 -> 5
    float v[NJ];
    #pragma unroll
    for (int c = 0; c < NP; ++c) {
        v[2 * c] = __low2float(acc[c]);
        if (2 * c + 1 < NJ) v[2 * c + 1] = __high2float(acc[c]);
    }
    #pragma unroll
    for (int j = 0; j < NJ; ++j) {
        DPPADD(v[j], 0xB1,  0xf);   // xor 1
        DPPADD(v[j], 0x4E,  0xf);   // xor 2
        DPPADD(v[j], 0x141, 0xf);   // row_half_mirror (xor 4)
        DPPADD(v[j], 0x140, 0xf);   // row_mirror      (xor 8)
        DPPADD(v[j], 0x142, 0xa);   // row_bcast:15 -> rows 1,3
        DPPADD(v[j], 0x143, 0xc);   // row_bcast:31 -> rows 2,3
    }
    if (lane == 63) {
        float best = v[0];
        #pragma unroll
        for (int j = 1; j < NJ; ++j) best = fminf(best, v[j]);
        atomicMin(sm, __float_as_uint(best));   // scores >= 0: uint order == float order
    }
}

template<int NBY, int NP>
__device__ __forceinline__ void proc(const __half2* __restrict__ winh, int (&addr)[4],
                                     const __half2 (&wx0)[4], const __half2 (&wx1)[4],
                                     const __half2 (&wy0n)[4], const __half2 (&wy1n)[4],
                                     const __half2 (&r1s)[4],
                                     unsigned* __restrict__ sm, int lane)
{
    __half2 hA[4][NP], hB[4][NP];
    rowload<NP>(winh, addr, wx0, wx1, hA);
    #pragma unroll
    for (int by = 0; by < NBY + 1; by += 2) {
        rowload<NP>(winh, addr, wx0, wx1, hB);
        bystep<NP>(hA, hB, wy0n, wy1n, r1s, sm, lane);
        if (by + 1 < NBY + 1) {
            rowload<NP>(winh, addr, wx0, wx1, hA);
            bystep<NP>(hB, hA, wy0n, wy1n, r1s, sm, lane);
        }
    }
}

// One block per image, 8 waves (512 threads) -> 32 waves/CU. Item = (angle,
// sub), 18/wave. Pixels are phase-aware bank-permuted per angle (build_table);
// r1 is gathered per item with offsets precomputed at angle reload (L1-hot).
__global__ __launch_bounds__(512) void randip_main(const float* __restrict__ fm1,
                                                   const float* __restrict__ fm2,
                                                   const uint4* __restrict__ gt,
                                                   float* __restrict__ out)
{
    __shared__ __half2 winh[WINSZH];    // 20160 B: pair c = (w[c-1], w[c]), f16
    __shared__ unsigned submin[16];

    const int b    = blockIdx.x;
    const int tid  = threadIdx.x;
    const int wave = tid >> 6;
    const int lane = tid & 63;

    for (int i = tid; i < WINSZH; i += 512) winh[i] = __floats2half2_rn(0.f, 0.f);
    if (tid < 16) submin[tid] = FLTMAX_BITS;
    __syncthreads();

    // fill pair-window: buffer (r+1, c) = (img2[r][c-1], img2[r][c])
    const float* img2 = fm2 + (size_t)b * 4096;
    for (int i = tid; i < 64 * 65; i += 512) {
        int r = i / 65, c = i - r * 65;
        float lo = (c >= 1)  ? img2[r * 64 + c - 1] : 0.f;
        float hi = (c <= 63) ? img2[r * 64 + c]     : 0.f;
        winh[(r + 1) * WSH + c] = __floats2half2_rn(lo, hi);
    }
    __syncthreads();

    const float* img1 = fm1 + (size_t)b * 4096;

    int a_cur = -1;
    __half2 wx0[4], wx1[4], wy0n[4], wy1n[4], r1s[4];
    float   sca[4];
    int     off[4], o1[4];

    for (int i = wave * IPW; i < (wave + 1) * IPW; ++i) {
        const int a = i >> 4, sub = i & 15;
        if (a != a_cur) {                     // <=2 reloads per wave, coalesced b128
            a_cur = a;
            const uint4* tp = gt + a * NPIX + lane;
            #pragma unroll
            for (int k = 0; k < 4; ++k) {
                uint4 te = tp[64 * k];
                __half2 X = *(const __half2*)&te.x;
                __half2 Y = *(const __half2*)&te.y;
                wx0[k]  = __half2half2(__low2half(X));
                wx1[k]  = __half2half2(__high2half(X));
                wy0n[k] = __half2half2(__low2half(Y));
                wy1n[k] = __half2half2(__high2half(Y));
                sca[k]  = __uint_as_float(te.z);
                off[k]  = (int)(te.w & 0xffffu);
                const int p = (int)(te.w >> 16);
                o1[k]  = (p >> 4) * 64 + (p & 15);   // img1-relative pixel offset
            }
        }
        const int sub_x = (sub & 3) << 4;
        const int sub_y = (sub >> 2) << 4;
        const int x_lo = max(sub_x - 4, 0);
        const int y_lo = max(sub_y - 4, 0);
        const int nvx = min(sub_x + 4, 48) - x_lo;   // 4 or 8
        const int nby = min(sub_y + 4, 48) - y_lo;   // 4 or 8
        const int rowbase0 = y_lo * WSH + x_lo;

        const float* img1sub = img1 + sub_y * 64 + sub_x;
        #pragma unroll
        for (int k = 0; k < 4; ++k)
            r1s[k] = __float2half2_rn(sca[k] * img1sub[o1[k]]);   // L1-hot gather

        int addr[4];
        #pragma unroll
        for (int k = 0; k < 4; ++k) addr[k] = rowbase0 + off[k];

        unsigned* sm = &submin[sub];
        if (nby == 8) {
            if (nvx == 8) proc<8, 5>(winh, addr, wx0, wx1, wy0n, wy1n, r1s, sm, lane);
            else          proc<8, 3>(winh, addr, wx0, wx1, wy0n, wy1n, r1s, sm, lane);
        } else {
            if (nvx == 8) proc<4, 5>(winh, addr, wx0, wx1, wy0n, wy1n, r1s, sm, lane);
            else          proc<4, 3>(winh, addr, wx0, wx1, wy0n, wy1n, r1s, sm, lane);
        }
    }
    __syncthreads();

    if (tid == 0) {
        float t = 0.0f;
        #pragma unroll
        for (int s = 0; s < 16; ++s) t += __uint_as_float(submin[s]);
        out[b] = t;
    }
}

extern "C" void kernel_launch(void* const* d_in, const int* in_sizes, int n_in,
                              void* d_out, int out_size, void* d_ws, size_t ws_size,
                              hipStream_t stream)
{
    const float* fm1 = (const float*)d_in[0];
    const float* fm2 = (const float*)d_in[1];
    float* out = (float*)d_out;
    uint4* tbl = (uint4*)d_ws;   // 36,864 B scratch

    const int nb = in_sizes[0] >> 12;   // 1024 images of 64*64

    hipLaunchKernelGGL(build_table, dim3(NANG), dim3(256), 0, stream, tbl);
    hipLaunchKernelGGL(randip_main, dim3(nb), dim3(512), 0, stream, fm1, fm2, tbl, out);
}

// Round 14
// 309.982 us; speedup vs baseline: 1.3961x; 1.1054x over previous
//
#include <hip/hip_runtime.h>
#include <hip/hip_fp16.h>
#include <math.h>

#define NANG 9
#define SS 16
#define NPIX 256
#define WSH 72                 // window row stride in half2 pairs; 72 mod 32 = 8
#define NROWW 70
#define WINSZH (NROWW * WSH)   // 5040 pair-dwords = 20160 B
#define NITEM (NANG * 16)      // 144 (angle, sub) items per image
#define NWAVE 8                // 512-thread blocks -> 4 blocks/CU x 8 waves = 32 waves/CU
#define IPW (NITEM / NWAVE)    // 18 items per wave
#define FLTMAX_BITS 0x7F7FFFFFu

// 16B per (angle, lane-slot):  (pixels are PERMUTED per angle for bank balance)
//  .x = half2 (ewx0, ewx1)           x-weights, block-validity folded in
//  .y = half2 (-s*ewy0, -s*ewy1)     NEGATED y-weights pre-scaled by s = sqrt(m/msum)
//  .z = f32 s
//  .w = off | (p << 16);  off = (y0+1)*WSH + (x0+1), p = original pixel index

// One block per ANGLE (grid=9): removes the 9x serialization (R11 post-mortem).
__global__ __launch_bounds__(256) void build_table(uint4* __restrict__ tbl)
{
    __shared__ float red[256];
    __shared__ int histo[4 * 32];      // per-wave per-class counts
    __shared__ int startArr[32];

    const int a  = blockIdx.x;
    const int p  = threadIdx.x;
    const int wv = p >> 6, ln = p & 63;
    const int px = p & 15, py = p >> 4;

    double t  = (double)(a - 4) * 0.017453292519943295; // deg2rad
    double ca = cos(t), sa = sin(t);
    float sx = (float)(ca * px - sa * py + (1.0 - ca) * 8.0 + sa * 8.0);
    float sy = (float)(sa * px + ca * py - sa * 8.0 + (1.0 - ca) * 8.0);
    float x0f = floorf(sx), y0f = floorf(sy);
    int   x0  = (int)x0f,   y0  = (int)y0f;
    float wx1 = sx - x0f, wx0 = 1.0f - wx1;
    float wy1 = sy - y0f, wy0 = 1.0f - wy1;
    float ewx0 = (x0 >= 0 && x0 < SS)         ? wx0 : 0.0f;
    float ewx1 = (x0 + 1 >= 0 && x0 + 1 < SS) ? wx1 : 0.0f;
    float ewy0 = (y0 >= 0 && y0 < SS)         ? wy0 : 0.0f;
    float ewy1 = (y0 + 1 >= 0 && y0 + 1 < SS) ? wy1 : 0.0f;
    float m = (ewx0 + ewx1) * (ewy0 + ewy1);

    red[p] = m;
    __syncthreads();
    for (int s = 128; s > 0; s >>= 1) {
        if (p < s) red[p] += red[p + s];
        __syncthreads();
    }
    float msum = red[0];

    float sc = sqrtf(m / msum);
    x0 = max(-1, min(15, x0));   // LDS bounds safety (weights encode validity)
    y0 = max(-1, min(15, y0));
    const int off = (y0 + 1) * WSH + (x0 + 1);
    uint4 e;
    e.x = (unsigned)__half_as_ushort(__float2half(ewx0)) |
          ((unsigned)__half_as_ushort(__float2half(ewx1)) << 16);
    e.y = (unsigned)__half_as_ushort(__float2half(-sc * ewy0)) |
          ((unsigned)__half_as_ushort(__float2half(-sc * ewy1)) << 16);
    e.z = __float_as_uint(sc);
    e.w = (unsigned)off | ((unsigned)p << 16);

    // per-angle pixel permutation: phase-split bank balancing (R9/R10: 10x
    // conflict cut). s -> k-group = s&3, lane = (s>>3) + 32*((s>>2)&1).
    const int cls = off & 31;
    unsigned long long mymask = 0;
    #pragma unroll
    for (int c = 0; c < 32; ++c) {
        unsigned long long mm = __ballot(cls == c);
        if (cls == c) mymask = mm;
        if (ln == c) histo[wv * 32 + c] = (int)__popcll(mm);
    }
    __syncthreads();
    int rank = (int)__popcll(mymask & ((1ull << ln) - 1ull));
    #pragma unroll
    for (int w = 0; w < 4; ++w)
        if (w < wv) rank += histo[w * 32 + cls];
    if (p < 32) {                        // start[c] = prefix of class totals
        int acc = 0;
        for (int c = 0; c < 32; ++c) {
            if (c == p) break;
            acc += histo[c] + histo[32 + c] + histo[64 + c] + histo[96 + c];
        }
        startArr[p] = acc;
    }
    __syncthreads();
    const int s      = startArr[cls] + rank;   // sorted-by-class position
    const int lane_n = (s >> 3) + (((s >> 2) & 1) << 5);
    const int nidx   = (s & 3) * 64 + lane_n;  // k-group, phase-split lane
    tbl[a * NPIX + nidx] = e;
}

// DPP helpers. NOTE (R13 lesson): 0x141/0x140 are MIRRORS (l^7 / l^15), valid
// as xor4/xor8 ONLY on values already uniform in the lower folded bits.
#define DPPADD(v, ctrl, rmask)                                                   \
    v += __int_as_float(__builtin_amdgcn_update_dpp(                             \
            0, __float_as_int(v), ctrl, rmask, 0xf, true))
#define DPPMINF(v, ctrl)                                                         \
    v = fminf(v, __int_as_float(__builtin_amdgcn_update_dpp(                     \
            0, __float_as_int(v), ctrl, 0xf, 0xf, true)))
#define SWZ16ADD(v)                                                              \
    v += __int_as_float(__builtin_amdgcn_ds_swizzle(__float_as_int(v), 0x401F))
#define XOR32ADD(v) v += __shfl_xor(v, 32, 64)

// Load one pair-row per k and packed-x-interp into h[k][0..NP-1] (half2 pairs).
template<int NP>
__device__ __forceinline__ void rowload(const __half2* __restrict__ winh,
                                        int (&addr)[4],
                                        const __half2 (&wx0)[4], const __half2 (&wx1)[4],
                                        __half2 (&h)[4][NP])
{
    #pragma unroll
    for (int k = 0; k < 4; ++k) {
        __half2 d[2 * NP];
        #pragma unroll
        for (int j = 0; j < 2 * NP; ++j) d[j] = winh[addr[k] + j];  // ds_read2_b32
        #pragma unroll
        for (int c = 0; c < NP; ++c)
            h[k][c] = __hfma2(wx1[k], d[2 * c + 1], __hmul2(wx0[k], d[2 * c]));
        addr[k] += WSH;
    }
}

// One by-step: packed y-interp + square-acc, then reduction:
//  (1) 4 mirror-butterfly stages per candidate register (R2-R12 pattern) ->
//      each v[j] uniform within its 16-lane row;
//  (2) MERGE: row-uniform values let lane bits 0-3 address candidates
//      (cndmask tree), z = candidate (lane&15)'s row-sum;
//  (3) TRUE xor16 (ds_swizzle 0x401F) + xor32 (shfl) finish the 64-lane sum
//      while preserving candidate bits 0-3;
//  (4) min over candidate positions via DPPMIN (mirrors valid again by
//      progressive low-bit uniformity of the min).
template<int NP>
__device__ __forceinline__ void bystep(const __half2 (&hp)[4][NP], const __half2 (&hc)[4][NP],
                                       const __half2 (&wy0n)[4], const __half2 (&wy1n)[4],
                                       const __half2 (&r1s)[4],
                                       unsigned* __restrict__ sm, int lane)
{
    __half2 acc[NP];
    #pragma unroll
    for (int c = 0; c < NP; ++c) acc[c] = __floats2half2_rn(0.f, 0.f);
    #pragma unroll
    for (int k = 0; k < 4; ++k) {
        #pragma unroll
        for (int c = 0; c < NP; ++c) {
            __half2 e = __hfma2(wy0n[k], hp[k][c], r1s[k]);  // r1s - wys0*hp
            e = __hfma2(wy1n[k], hc[k][c], e);               //     - wys1*hc
            acc[c] = __hfma2(e, e, acc[c]);
        }
    }
    constexpr int NJ = 2 * NP - 1;     // valid bx count: NP=5 -> 9, NP=3 -> 5
    float v[NJ];
    #pragma unroll
    for (int c = 0; c < NP; ++c) {
        v[2 * c] = __low2float(acc[c]);
        if (2 * c + 1 < NJ) v[2 * c + 1] = __high2float(acc[c]);
    }
    #pragma unroll
    for (int j = 0; j < NJ; ++j) {
        DPPADD(v[j], 0xB1,  0xf);   // xor1
        DPPADD(v[j], 0x4E,  0xf);   // xor2
        DPPADD(v[j], 0x141, 0xf);   // mirror l^7  == xor4 (bits 0-1 uniform)
        DPPADD(v[j], 0x140, 0xf);   // mirror l^15 == xor8 (bits 0-2 uniform)
    }
    float z;
    if constexpr (NP == 5) {
        float t01 = (lane & 1) ? v[1] : v[0];
        float t23 = (lane & 1) ? v[3] : v[2];
        float t45 = (lane & 1) ? v[5] : v[4];
        float t67 = (lane & 1) ? v[7] : v[6];
        float q03 = (lane & 2) ? t23 : t01;
        float q47 = (lane & 2) ? t67 : t45;
        float o   = (lane & 4) ? q47 : q03;
        z         = (lane & 8) ? v[8] : o;   // pos p=lane&15: cand p&7 (p<8) else 8
    } else {
        float t01 = (lane & 1) ? v[1] : v[0];
        float t23 = (lane & 1) ? v[3] : v[2];
        float q   = (lane & 2) ? t23 : t01;
        z         = (lane & 4) ? v[4] : q;   // pos: cand lane&3 (bit2=0) else 4
    }
    SWZ16ADD(z);                    // true xor16 (within 32-half), keeps bits 0-3
    XOR32ADD(z);                    // true xor32 -> full 64-lane sum per candidate
    DPPMINF(z, 0xB1);               // fold bit0
    DPPMINF(z, 0x4E);               // fold bit1
    DPPMINF(z, 0x141);              // == xor4 fold (bits 0-1 min-uniform)
    if constexpr (NP == 5) DPPMINF(z, 0x140);   // == xor8 fold
    if (lane == 63)
        atomicMin(sm, __float_as_uint(z));   // scores >= 0: uint order == float order
}

template<int NBY, int NP>
__device__ __forceinline__ void proc(const __half2* __restrict__ winh, int (&addr)[4],
                                     const __half2 (&wx0)[4], const __half2 (&wx1)[4],
                                     const __half2 (&wy0n)[4], const __half2 (&wy1n)[4],
                                     const __half2 (&r1s)[4],
                                     unsigned* __restrict__ sm, int lane)
{
    __half2 hA[4][NP], hB[4][NP];
    rowload<NP>(winh, addr, wx0, wx1, hA);
    #pragma unroll
    for (int by = 0; by < NBY + 1; by += 2) {
        rowload<NP>(winh, addr, wx0, wx1, hB);
        bystep<NP>(hA, hB, wy0n, wy1n, r1s, sm, lane);
        if (by + 1 < NBY + 1) {
            rowload<NP>(winh, addr, wx0, wx1, hA);
            bystep<NP>(hB, hA, wy0n, wy1n, r1s, sm, lane);
        }
    }
}

// One block per image, 8 waves (512 threads) -> 32 waves/CU. Item = (angle,
// sub), 18/wave. Pixels are phase-aware bank-permuted per angle (build_table);
// r1 is gathered per item with offsets precomputed at angle reload (L1-hot).
__global__ __launch_bounds__(512) void randip_main(const float* __restrict__ fm1,
                                                   const float* __restrict__ fm2,
                                                   const uint4* __restrict__ gt,
                                                   float* __restrict__ out)
{
    __shared__ __half2 winh[WINSZH];    // 20160 B: pair c = (w[c-1], w[c]), f16
    __shared__ unsigned submin[16];

    const int b    = blockIdx.x;
    const int tid  = threadIdx.x;
    const int wave = tid >> 6;
    const int lane = tid & 63;

    for (int i = tid; i < WINSZH; i += 512) winh[i] = __floats2half2_rn(0.f, 0.f);
    if (tid < 16) submin[tid] = FLTMAX_BITS;
    __syncthreads();

    // fill pair-window: buffer (r+1, c) = (img2[r][c-1], img2[r][c])
    const float* img2 = fm2 + (size_t)b * 4096;
    for (int i = tid; i < 64 * 65; i += 512) {
        int r = i / 65, c = i - r * 65;
        float lo = (c >= 1)  ? img2[r * 64 + c - 1] : 0.f;
        float hi = (c <= 63) ? img2[r * 64 + c]     : 0.f;
        winh[(r + 1) * WSH + c] = __floats2half2_rn(lo, hi);
    }
    __syncthreads();

    const float* img1 = fm1 + (size_t)b * 4096;

    int a_cur = -1;
    __half2 wx0[4], wx1[4], wy0n[4], wy1n[4], r1s[4];
    float   sca[4];
    int     off[4], o1[4];

    for (int i = wave * IPW; i < (wave + 1) * IPW; ++i) {
        const int a = i >> 4, sub = i & 15;
        if (a != a_cur) {                     // <=2 reloads per wave, coalesced b128
            a_cur = a;
            const uint4* tp = gt + a * NPIX + lane;
            #pragma unroll
            for (int k = 0; k < 4; ++k) {
                uint4 te = tp[64 * k];
                __half2 X = *(const __half2*)&te.x;
                __half2 Y = *(const __half2*)&te.y;
                wx0[k]  = __half2half2(__low2half(X));
                wx1[k]  = __half2half2(__high2half(X));
                wy0n[k] = __half2half2(__low2half(Y));
                wy1n[k] = __half2half2(__high2half(Y));
                sca[k]  = __uint_as_float(te.z);
                off[k]  = (int)(te.w & 0xffffu);
                const int p = (int)(te.w >> 16);
                o1[k]  = (p >> 4) * 64 + (p & 15);   // img1-relative pixel offset
            }
        }
        const int sub_x = (sub & 3) << 4;
        const int sub_y = (sub >> 2) << 4;
        const int x_lo = max(sub_x - 4, 0);
        const int y_lo = max(sub_y - 4, 0);
        const int nvx = min(sub_x + 4, 48) - x_lo;   // 4 or 8
        const int nby = min(sub_y + 4, 48) - y_lo;   // 4 or 8
        const int rowbase0 = y_lo * WSH + x_lo;

        const float* img1sub = img1 + sub_y * 64 + sub_x;
        #pragma unroll
        for (int k = 0; k < 4; ++k)
            r1s[k] = __float2half2_rn(sca[k] * img1sub[o1[k]]);   // L1-hot gather

        int addr[4];
        #pragma unroll
        for (int k = 0; k < 4; ++k) addr[k] = rowbase0 + off[k];

        unsigned* sm = &submin[sub];
        if (nby == 8) {
            if (nvx == 8) proc<8, 5>(winh, addr, wx0, wx1, wy0n, wy1n, r1s, sm, lane);
            else          proc<8, 3>(winh, addr, wx0, wx1, wy0n, wy1n, r1s, sm, lane);
        } else {
            if (nvx == 8) proc<4, 5>(winh, addr, wx0, wx1, wy0n, wy1n, r1s, sm, lane);
            else          proc<4, 3>(winh, addr, wx0, wx1, wy0n, wy1n, r1s, sm, lane);
        }
    }
    __syncthreads();

    if (tid == 0) {
        float t = 0.0f;
        #pragma unroll
        for (int s = 0; s < 16; ++s) t += __uint_as_float(submin[s]);
        out[b] = t;
    }
}

extern "C" void kernel_launch(void* const* d_in, const int* in_sizes, int n_in,
                              void* d_out, int out_size, void* d_ws, size_t ws_size,
                              hipStream_t stream)
{
    const float* fm1 = (const float*)d_in[0];
    const float* fm2 = (const float*)d_in[1];
    float* out = (float*)d_out;
    uint4* tbl = (uint4*)d_ws;   // 36,864 B scratch

    const int nb = in_sizes[0] >> 12;   // 1024 images of 64*64

    hipLaunchKernelGGL(build_table, dim3(NANG), dim3(256), 0, stream, tbl);
    hipLaunchKernelGGL(randip_main, dim3(nb), dim3(512), 0, stream, fm1, fm2, tbl, out);
}